// Round 2
// baseline (216.123 us; speedup 1.0000x reference)
//
#include <hip/hip_runtime.h>
#include <stdint.h>

#define DEVI static __device__ __forceinline__

typedef float f32x4 __attribute__((ext_vector_type(4)));
typedef short s16x8 __attribute__((ext_vector_type(8)));
typedef unsigned short u16x4 __attribute__((ext_vector_type(4)));

// f32 -> bf16 round-to-nearest-even
DEVI unsigned short f2bf(float f) {
  union { float f; uint32_t u; } v; v.f = f;
  uint32_t u = v.u;
  return (unsigned short)((u + 0x7fffu + ((u >> 16) & 1u)) >> 16);
}

// async 16B global -> LDS (linear dest: wave-uniform base + lane*16)
DEVI void g2l16(const void* g, void* l) {
  __builtin_amdgcn_global_load_lds(
      (const __attribute__((address_space(1))) void*)g,
      (__attribute__((address_space(3))) void*)l, 16, 0, 0);
}

// ---------------------------------------------------------------- convert
__global__ __launch_bounds__(256) void k_cvt(const float* __restrict__ in,
                                             unsigned short* __restrict__ out,
                                             int n) {
  int idx = blockIdx.x * blockDim.x + threadIdx.x;
  int stride = gridDim.x * blockDim.x;
  for (int i = idx * 4; i < n; i += stride * 4) {
    f32x4 v = *(const f32x4*)(in + i);
    u16x4 o;
    for (int j = 0; j < 4; ++j) o[j] = f2bf(v[j]);
    *(u16x4*)(out + i) = o;
  }
}

// ------------------------------------------- weight transpose+convert (1024x1024)
// w[k][n] f32  ->  wt[n][k] bf16
__global__ __launch_bounds__(256) void k_wt(const float* __restrict__ w,
                                            unsigned short* __restrict__ wt) {
  __shared__ float tile[32][33];
  const int tx = threadIdx.x, ty = threadIdx.y;
  const int n0 = blockIdx.x * 32, k0 = blockIdx.y * 32;
  for (int j = 0; j < 4; ++j)
    tile[ty + j * 8][tx] = w[(size_t)(k0 + ty + j * 8) * 1024 + n0 + tx];
  __syncthreads();
  for (int j = 0; j < 4; ++j)
    wt[(size_t)(n0 + ty + j * 8) * 1024 + k0 + tx] = f2bf(tile[tx][ty + j * 8]);
}

// ---------------------------------------------------------------- GEMM (bt)
// A[4096][1024] bf16, Bt[1024(n)][1024(k)] bf16, bias f32[1024]
// MODE 0: out bf16 [4096][1024], scaled by 0.125*log2(e) (Q projection)
// MODE 1: out bf16 [4096][1024]                         (K projection)
// MODE 2: out bf16 Vt[(b*1024+n)*2048 + t]              (V projection, transposed)
// MODE 3: out f32  [4096][1024]                         (output projection)
template <int MODE>
__global__ __launch_bounds__(256) void k_gemm(const unsigned short* __restrict__ A,
                                              const unsigned short* __restrict__ Bt,
                                              const float* __restrict__ bias,
                                              void* __restrict__ outp) {
  constexpr int K = 1024;
  __shared__ __align__(16) unsigned short As[128 * 64];
  __shared__ __align__(16) unsigned short Bs[64 * 64];
  const int tid = threadIdx.x;
  const int lane = tid & 63, w = tid >> 6;
  const int g = lane >> 4, c = lane & 15;
  const int bm = blockIdx.x >> 4, bn = blockIdx.x & 15;  // 32 x 16 blocks
  const int m0 = bm * 128, n0 = bn * 64;
  const int wr = w >> 1, wc = w & 1;  // wave tile: 64(m) x 32(n)
  f32x4 acc[4][2] = {};

  for (int kt = 0; kt < 16; ++kt) {
    const int k0 = kt * 64;
    __syncthreads();
    // stage A: 128x64 bf16 = 1024 x 16B chunks; pre-swizzled source, linear dest
    for (int it = 0; it < 4; ++it) {
      int e = it * 256 + tid;
      int row = e >> 3, cwp = (e & 7) ^ (row & 7);
      g2l16(A + (size_t)(m0 + row) * K + k0 + cwp * 8,
            (char*)As + (it * 256 + (w << 6)) * 16);
    }
    // stage B: 64x64 bf16 = 512 chunks
    for (int it = 0; it < 2; ++it) {
      int e = it * 256 + tid;
      int row = e >> 3, cwp = (e & 7) ^ (row & 7);
      g2l16(Bt + (size_t)(n0 + row) * K + k0 + cwp * 8,
            (char*)Bs + (it * 256 + (w << 6)) * 16);
    }
    __syncthreads();
    for (int kk = 0; kk < 2; ++kk) {
      s16x8 af[4], bfr[2];
      for (int mi = 0; mi < 4; ++mi) {
        int row = wr * 64 + mi * 16 + c;
        int ch = (kk * 4 + g) ^ (row & 7);
        af[mi] = *(const s16x8*)((const char*)As + row * 128 + ch * 16);
      }
      for (int ni = 0; ni < 2; ++ni) {
        int row = wc * 32 + ni * 16 + c;
        int ch = (kk * 4 + g) ^ (row & 7);
        bfr[ni] = *(const s16x8*)((const char*)Bs + row * 128 + ch * 16);
      }
      for (int mi = 0; mi < 4; ++mi)
        for (int ni = 0; ni < 2; ++ni)
          acc[mi][ni] = __builtin_amdgcn_mfma_f32_16x16x32_bf16(
              af[mi], bfr[ni], acc[mi][ni], 0, 0, 0);
    }
  }

  if constexpr (MODE == 0 || MODE == 1) {
    unsigned short* out = (unsigned short*)outp;
    const float scale = (MODE == 0) ? 0.1803368801111204f : 1.0f;  // 0.125*log2(e)
    for (int mi = 0; mi < 4; ++mi)
      for (int ni = 0; ni < 2; ++ni) {
        int row = m0 + wr * 64 + mi * 16 + g * 4;
        int col = n0 + wc * 32 + ni * 16 + c;
        float bb = bias[col];
        for (int r = 0; r < 4; ++r)
          out[(size_t)(row + r) * 1024 + col] = f2bf((acc[mi][ni][r] + bb) * scale);
      }
  } else if constexpr (MODE == 2) {
    // transpose C-tile via LDS -> Vt[n][t] with coalesced 16B stores
    __shared__ __align__(16) unsigned short Tr[64 * 136];
    for (int mi = 0; mi < 4; ++mi)
      for (int ni = 0; ni < 2; ++ni) {
        int rowl = wr * 64 + mi * 16 + g * 4;
        int coll = wc * 32 + ni * 16 + c;
        float bb = bias[n0 + coll];
        u16x4 pk;
        for (int r = 0; r < 4; ++r) pk[r] = f2bf(acc[mi][ni][r] + bb);
        *(u16x4*)&Tr[coll * 136 + rowl] = pk;
      }
    __syncthreads();
    unsigned short* vt = (unsigned short*)outp;
    const int b = m0 >> 11, t0 = m0 & 2047;
    for (int it = 0; it < 4; ++it) {
      int e = it * 256 + tid;  // 64 n x 16 chunks(8 elems)
      int nl = e >> 4, tc = (e & 15) * 8;
      s16x8 vv = *(const s16x8*)&Tr[nl * 136 + tc];
      *(s16x8*)(vt + (size_t)(b * 1024 + n0 + nl) * 2048 + t0 + tc) = vv;
    }
  } else {
    float* out = (float*)outp;
    for (int mi = 0; mi < 4; ++mi)
      for (int ni = 0; ni < 2; ++ni) {
        int row = m0 + wr * 64 + mi * 16 + g * 4;
        int col = n0 + wc * 32 + ni * 16 + c;
        float bb = bias[col];
        for (int r = 0; r < 4; ++r)
          out[(size_t)(row + r) * 1024 + col] = acc[mi][ni][r] + bb;
      }
  }
}

// ---------------------------------------------------------------- attention
// Qp/Kp: [B*T][1024] bf16 (Qp pre-scaled by 0.125*log2e), Vt: [(b*1024+n)][2048] bf16
// Att out: [B*T][1024] bf16
__global__ __launch_bounds__(256) void k_attn(const unsigned short* __restrict__ Qp,
                                              const unsigned short* __restrict__ Kp,
                                              const unsigned short* __restrict__ Vt,
                                              unsigned short* __restrict__ Att) {
  __shared__ __align__(16) unsigned short Ks[64 * 64];  // [key][d], swizzled
  __shared__ __align__(16) unsigned short Vs[64 * 64];  // [d][key], swizzled
  __shared__ __align__(16) unsigned short Pl[4 * 16 * 72];  // per-wave P [16][72]
  const int tid = threadIdx.x;
  const int lane = tid & 63, w = tid >> 6;
  const int g = lane >> 4, c = lane & 15;
  const int blk = blockIdx.x;
  const int qt = blk & 31, bh = blk >> 5;
  const int b = bh >> 4, h = bh & 15;
  const int m0 = qt * 64 + w * 16;  // q-row base of this wave
  const size_t qkBase = (size_t)b * 2048 * 1024 + (size_t)h * 64;
  const size_t vtBase = ((size_t)b * 1024 + h * 64) * 2048;
  unsigned short* pl = Pl + w * (16 * 72);

  // Q fragments in registers (scaled at projection)
  s16x8 aq[2];
  for (int kk = 0; kk < 2; ++kk)
    aq[kk] = *(const s16x8*)(Qp + qkBase + (size_t)(m0 + c) * 1024 + kk * 32 + g * 8);

  float m_run[4] = {-1e30f, -1e30f, -1e30f, -1e30f};
  float l_run[4] = {0.f, 0.f, 0.f, 0.f};
  f32x4 o[4] = {};

  for (int kb = 0; kb < 32; ++kb) {
    const int n0 = kb * 64;
    __syncthreads();
    // stage K tile [64 key][64 d] and V tile [64 d][64 key] (swizzled source)
    for (int it = 0; it < 2; ++it) {
      int e = it * 256 + tid;
      int row = e >> 3, cwp = (e & 7) ^ (row & 7);
      g2l16(Kp + qkBase + (size_t)(n0 + row) * 1024 + cwp * 8,
            (char*)Ks + (it * 256 + (w << 6)) * 16);
      g2l16(Vt + vtBase + (size_t)row * 2048 + n0 + cwp * 8,
            (char*)Vs + (it * 256 + (w << 6)) * 16);
    }
    __syncthreads();

    // S = Q K^T  (16 q x 64 keys), C-layout: col=key=c, row=q=4g+r
    f32x4 s[4] = {};
    for (int nt = 0; nt < 4; ++nt) {
      for (int kk = 0; kk < 2; ++kk) {
        int row = nt * 16 + c;
        int ch = (kk * 4 + g) ^ (row & 7);
        s16x8 bk = *(const s16x8*)((const char*)Ks + row * 128 + ch * 16);
        s[nt] = __builtin_amdgcn_mfma_f32_16x16x32_bf16(aq[kk], bk, s[nt], 0, 0, 0);
      }
    }

    // online softmax (log2 domain; scale folded into Q)
    float mt[4], alpha[4], rs[4];
    for (int r = 0; r < 4; ++r) {
      float v = fmaxf(fmaxf(s[0][r], s[1][r]), fmaxf(s[2][r], s[3][r]));
      v = fmaxf(v, __shfl_xor(v, 1));
      v = fmaxf(v, __shfl_xor(v, 2));
      v = fmaxf(v, __shfl_xor(v, 4));
      v = fmaxf(v, __shfl_xor(v, 8));
      mt[r] = fmaxf(v, m_run[r]);
      alpha[r] = exp2f(m_run[r] - mt[r]);
      rs[r] = 0.f;
    }
    for (int nt = 0; nt < 4; ++nt) {
      for (int r = 0; r < 4; ++r) {
        float p = exp2f(s[nt][r] - mt[r]);
        rs[r] += p;
        pl[(g * 4 + r) * 72 + nt * 16 + c] = f2bf(p);
      }
    }
    for (int r = 0; r < 4; ++r) {
      float v = rs[r];
      v += __shfl_xor(v, 1);
      v += __shfl_xor(v, 2);
      v += __shfl_xor(v, 4);
      v += __shfl_xor(v, 8);
      l_run[r] = l_run[r] * alpha[r] + v;
      m_run[r] = mt[r];
    }
    for (int dt = 0; dt < 4; ++dt)
      for (int r = 0; r < 4; ++r) o[dt][r] *= alpha[r];

    // O += P V : A = P[16 q][64 key] (LDS), B = V[key][d] via Vs[d][key]
    for (int kk = 0; kk < 2; ++kk) {
      s16x8 ap = *(const s16x8*)((const char*)pl + c * 144 + kk * 64 + g * 16);
      for (int dt = 0; dt < 4; ++dt) {
        int row = dt * 16 + c;
        int ch = (kk * 4 + g) ^ (row & 7);
        s16x8 bv = *(const s16x8*)((const char*)Vs + row * 128 + ch * 16);
        o[dt] = __builtin_amdgcn_mfma_f32_16x16x32_bf16(ap, bv, o[dt], 0, 0, 0);
      }
    }
  }

  // write Att[b][t][h*64 + d] bf16
  for (int r = 0; r < 4; ++r) {
    float inv = 1.0f / l_run[r];
    int t = m0 + g * 4 + r;
    size_t base = ((size_t)b * 2048 + t) * 1024 + h * 64;
    for (int dt = 0; dt < 4; ++dt)
      Att[base + dt * 16 + c] = f2bf(o[dt][r] * inv);
  }
}

// ---------------------------------------------------------------- launch
extern "C" void kernel_launch(void* const* d_in, const int* in_sizes, int n_in,
                              void* d_out, int out_size, void* d_ws, size_t ws_size,
                              hipStream_t stream) {
  const float* q = (const float*)d_in[0];
  const float* k = (const float*)d_in[1];
  const float* v = (const float*)d_in[2];
  const float* w_q = (const float*)d_in[3];
  const float* b_q = (const float*)d_in[4];
  const float* w_k = (const float*)d_in[5];
  const float* b_k = (const float*)d_in[6];
  const float* w_v = (const float*)d_in[7];
  const float* b_v = (const float*)d_in[8];
  const float* w_o = (const float*)d_in[9];
  const float* b_o = (const float*)d_in[10];

  unsigned short* s = (unsigned short*)d_ws;
  unsigned short* qbf = s;                   // 4096x1024 (reused for Att later)
  unsigned short* kbf = s + 4194304;
  unsigned short* vbf = s + 8388608;
  unsigned short* wqT = s + 12582912;        // 1024x1024 each
  unsigned short* wkT = s + 13631488;
  unsigned short* wvT = s + 14680064;
  unsigned short* woT = s + 15728640;
  unsigned short* Qp  = s + 16777216;        // 4096x1024
  unsigned short* Kp  = s + 20971520;
  unsigned short* Vt  = s + 25165824;        // end: 29360128 shorts = 56 MiB
  unsigned short* Att = qbf;                 // alias: qbf dead after k_gemm<0>

  const int NQKV = 4194304;
  k_cvt<<<2048, 256, 0, stream>>>(q, qbf, NQKV);
  k_cvt<<<2048, 256, 0, stream>>>(k, kbf, NQKV);
  k_cvt<<<2048, 256, 0, stream>>>(v, vbf, NQKV);

  dim3 tb(32, 8), tg(32, 32);
  k_wt<<<tg, tb, 0, stream>>>(w_q, wqT);
  k_wt<<<tg, tb, 0, stream>>>(w_k, wkT);
  k_wt<<<tg, tb, 0, stream>>>(w_v, wvT);
  k_wt<<<tg, tb, 0, stream>>>(w_o, woT);

  k_gemm<0><<<512, 256, 0, stream>>>(qbf, wqT, b_q, (void*)Qp);
  k_gemm<1><<<512, 256, 0, stream>>>(kbf, wkT, b_k, (void*)Kp);
  k_gemm<2><<<512, 256, 0, stream>>>(vbf, wvT, b_v, (void*)Vt);

  k_attn<<<1024, 256, 0, stream>>>(Qp, Kp, Vt, Att);

  k_gemm<3><<<512, 256, 0, stream>>>(Att, woT, b_o, d_out);
}

// Round 3
// 166.682 us; speedup vs baseline: 1.2966x; 1.2966x over previous
//
#include <hip/hip_runtime.h>
#include <stdint.h>

#define DEVI static __device__ __forceinline__

typedef float f32x4 __attribute__((ext_vector_type(4)));
typedef short s16x8 __attribute__((ext_vector_type(8)));
typedef unsigned short u16x4 __attribute__((ext_vector_type(4)));
typedef uint32_t u32x2 __attribute__((ext_vector_type(2)));

// f32 -> bf16 round-to-nearest-even
DEVI unsigned short f2bf(float f) {
  union { float f; uint32_t u; } v; v.f = f;
  uint32_t u = v.u;
  return (unsigned short)((u + 0x7fffu + ((u >> 16) & 1u)) >> 16);
}

// packed f32x2 -> bf16x2 (gfx950 v_cvt_pk_bf16_f32, RNE)
DEVI uint32_t cvtpk_bf16(float lo, float hi) {
  uint32_t r;
  asm("v_cvt_pk_bf16_f32 %0, %1, %2" : "=v"(r) : "v"(lo), "v"(hi));
  return r;
}

// async 16B global -> LDS (linear dest: wave-uniform base + lane*16)
DEVI void g2l16(const void* g, void* l) {
  __builtin_amdgcn_global_load_lds(
      (const __attribute__((address_space(1))) void*)g,
      (__attribute__((address_space(3))) void*)l, 16, 0, 0);
}

// ---------------------------------------------------------------- convert
__global__ __launch_bounds__(256) void k_cvt(const float* __restrict__ in,
                                             unsigned short* __restrict__ out,
                                             int n) {
  int idx = blockIdx.x * blockDim.x + threadIdx.x;
  int stride = gridDim.x * blockDim.x;
  for (int i = idx * 4; i < n; i += stride * 4) {
    f32x4 v = *(const f32x4*)(in + i);
    u16x4 o;
    for (int j = 0; j < 4; ++j) o[j] = f2bf(v[j]);
    *(u16x4*)(out + i) = o;
  }
}

// ------------------------------------------- weight transpose+convert (1024x1024)
// w[k][n] f32  ->  wt[n][k] bf16
__global__ __launch_bounds__(256) void k_wt(const float* __restrict__ w,
                                            unsigned short* __restrict__ wt) {
  __shared__ float tile[32][33];
  const int tx = threadIdx.x, ty = threadIdx.y;
  const int n0 = blockIdx.x * 32, k0 = blockIdx.y * 32;
  for (int j = 0; j < 4; ++j)
    tile[ty + j * 8][tx] = w[(size_t)(k0 + ty + j * 8) * 1024 + n0 + tx];
  __syncthreads();
  for (int j = 0; j < 4; ++j)
    wt[(size_t)(n0 + ty + j * 8) * 1024 + k0 + tx] = f2bf(tile[tx][ty + j * 8]);
}

// ---------------------------------------------------------------- GEMM (bt)
// A[4096][1024] bf16, Bt[1024(n)][1024(k)] bf16, bias f32[1024]
// MODE 0: out bf16 [4096][1024], scaled by 0.125*log2(e) (Q projection)
// MODE 1: out bf16 [4096][1024]                         (K projection)
// MODE 2: out bf16 Vt[(b*1024+n)*2048 + t]              (V projection, transposed)
// MODE 3: out f32  [4096][1024]                         (output projection)
template <int MODE>
__global__ __launch_bounds__(256) void k_gemm(const unsigned short* __restrict__ A,
                                              const unsigned short* __restrict__ Bt,
                                              const float* __restrict__ bias,
                                              void* __restrict__ outp) {
  constexpr int K = 1024;
  __shared__ __align__(16) unsigned short As[128 * 64];
  __shared__ __align__(16) unsigned short Bs[64 * 64];
  const int tid = threadIdx.x;
  const int lane = tid & 63, w = tid >> 6;
  const int g = lane >> 4, c = lane & 15;
  const int bm = blockIdx.x >> 4, bn = blockIdx.x & 15;  // 32 x 16 blocks
  const int m0 = bm * 128, n0 = bn * 64;
  const int wr = w >> 1, wc = w & 1;  // wave tile: 64(m) x 32(n)
  f32x4 acc[4][2] = {};

  for (int kt = 0; kt < 16; ++kt) {
    const int k0 = kt * 64;
    __syncthreads();
    // stage A: 128x64 bf16 = 1024 x 16B chunks; pre-swizzled source, linear dest
    for (int it = 0; it < 4; ++it) {
      int e = it * 256 + tid;
      int row = e >> 3, cwp = (e & 7) ^ (row & 7);
      g2l16(A + (size_t)(m0 + row) * K + k0 + cwp * 8,
            (char*)As + (it * 256 + (w << 6)) * 16);
    }
    // stage B: 64x64 bf16 = 512 chunks
    for (int it = 0; it < 2; ++it) {
      int e = it * 256 + tid;
      int row = e >> 3, cwp = (e & 7) ^ (row & 7);
      g2l16(Bt + (size_t)(n0 + row) * K + k0 + cwp * 8,
            (char*)Bs + (it * 256 + (w << 6)) * 16);
    }
    __syncthreads();
    for (int kk = 0; kk < 2; ++kk) {
      s16x8 af[4], bfr[2];
      for (int mi = 0; mi < 4; ++mi) {
        int row = wr * 64 + mi * 16 + c;
        int ch = (kk * 4 + g) ^ (row & 7);
        af[mi] = *(const s16x8*)((const char*)As + row * 128 + ch * 16);
      }
      for (int ni = 0; ni < 2; ++ni) {
        int row = wc * 32 + ni * 16 + c;
        int ch = (kk * 4 + g) ^ (row & 7);
        bfr[ni] = *(const s16x8*)((const char*)Bs + row * 128 + ch * 16);
      }
      for (int mi = 0; mi < 4; ++mi)
        for (int ni = 0; ni < 2; ++ni)
          acc[mi][ni] = __builtin_amdgcn_mfma_f32_16x16x32_bf16(
              af[mi], bfr[ni], acc[mi][ni], 0, 0, 0);
    }
  }

  if constexpr (MODE == 0 || MODE == 1) {
    unsigned short* out = (unsigned short*)outp;
    const float scale = (MODE == 0) ? 0.1803368801111204f : 1.0f;  // 0.125*log2(e)
    for (int mi = 0; mi < 4; ++mi)
      for (int ni = 0; ni < 2; ++ni) {
        int row = m0 + wr * 64 + mi * 16 + g * 4;
        int col = n0 + wc * 32 + ni * 16 + c;
        float bb = bias[col];
        for (int r = 0; r < 4; ++r)
          out[(size_t)(row + r) * 1024 + col] = f2bf((acc[mi][ni][r] + bb) * scale);
      }
  } else if constexpr (MODE == 2) {
    // transpose C-tile via LDS -> Vt[n][t] with coalesced 16B stores
    __shared__ __align__(16) unsigned short Tr[64 * 136];
    for (int mi = 0; mi < 4; ++mi)
      for (int ni = 0; ni < 2; ++ni) {
        int rowl = wr * 64 + mi * 16 + g * 4;
        int coll = wc * 32 + ni * 16 + c;
        float bb = bias[n0 + coll];
        u16x4 pk;
        for (int r = 0; r < 4; ++r) pk[r] = f2bf(acc[mi][ni][r] + bb);
        *(u16x4*)&Tr[coll * 136 + rowl] = pk;
      }
    __syncthreads();
    unsigned short* vt = (unsigned short*)outp;
    const int b = m0 >> 11, t0 = m0 & 2047;
    for (int it = 0; it < 4; ++it) {
      int e = it * 256 + tid;  // 64 n x 16 chunks(8 elems)
      int nl = e >> 4, tc = (e & 15) * 8;
      s16x8 vv = *(const s16x8*)&Tr[nl * 136 + tc];
      *(s16x8*)(vt + (size_t)(b * 1024 + n0 + nl) * 2048 + t0 + tc) = vv;
    }
  } else {
    float* out = (float*)outp;
    for (int mi = 0; mi < 4; ++mi)
      for (int ni = 0; ni < 2; ++ni) {
        int row = m0 + wr * 64 + mi * 16 + g * 4;
        int col = n0 + wc * 32 + ni * 16 + c;
        float bb = bias[col];
        for (int r = 0; r < 4; ++r)
          out[(size_t)(row + r) * 1024 + col] = acc[mi][ni][r] + bb;
      }
  }
}

// ---------------------------------------------------------------- attention
// Swapped-QK^T flash attention: S^T = mfma(K,Q) puts one q-row per lane
// (q = lane&15); softmax fully in-register (2 shfl per reduce); P packed via
// v_cvt_pk + one ds_write_b64 per nt; PV computes O^T[d][q] so the lane's
// accumulator column matches its softmax state. K/V double-buffered, one
// barrier per tile (stage overlapped with compute).
__global__ __launch_bounds__(256, 4) void k_attn(const unsigned short* __restrict__ Qp,
                                                 const unsigned short* __restrict__ Kp,
                                                 const unsigned short* __restrict__ Vt,
                                                 unsigned short* __restrict__ Att) {
  __shared__ __align__(16) unsigned short Ks[2][4096];  // [key][d] swizzled
  __shared__ __align__(16) unsigned short Vs[2][4096];  // [d][key] swizzled
  __shared__ __align__(16) unsigned short Pw[4][1024];  // per-wave P[q=c][key] swizzled
  const int tid = threadIdx.x;
  const int lane = tid & 63, w = tid >> 6;
  const int g = lane >> 4, c = lane & 15;
  // XCD-chunked swizzle: XCD x hosts blk in [x*128, (x+1)*128) = 4 contiguous bh
  const int blk = (blockIdx.x & 7) * 128 + (blockIdx.x >> 3);
  const int qt = blk & 31, bh = blk >> 5;
  const int b = bh >> 4, h = bh & 15;
  const int m0 = qt * 64 + w * 16;  // q-row base of this wave
  const size_t qkBase = (size_t)b * 2048 * 1024 + (size_t)h * 64;
  const size_t vtBase = ((size_t)b * 1024 + h * 64) * 2048;

  // Q fragment (B-operand): lane holds Q[q=m0+c][d = kk*32 + g*8 .. +7]
  s16x8 aq[2];
  for (int kk = 0; kk < 2; ++kk)
    aq[kk] = *(const s16x8*)(Qp + qkBase + (size_t)(m0 + c) * 1024 + kk * 32 + g * 8);

  // staging source pointers (per-thread, pre-swizzled)
  const int srow = tid >> 3;                 // 0..31 (it adds 32)
  const int scw = (tid & 7) ^ (srow & 7);    // same for it=0/1 (32 = 0 mod 8)
  const unsigned short* kSrc = Kp + qkBase + (size_t)srow * 1024 + scw * 8;
  const unsigned short* vSrc = Vt + vtBase + (size_t)srow * 2048 + scw * 8;
  const int ldst = (w << 6) * 16;            // wave-uniform LDS offset (+lane*16 by HW)

  auto stage = [&](int buf, int n0) {
    g2l16(kSrc + (size_t)n0 * 1024, (char*)&Ks[buf][0] + ldst);
    g2l16(kSrc + (size_t)n0 * 1024 + 32 * 1024, (char*)&Ks[buf][0] + 4096 + ldst);
    g2l16(vSrc + n0, (char*)&Vs[buf][0] + ldst);
    g2l16(vSrc + n0 + 32 * 2048, (char*)&Vs[buf][0] + 4096 + ldst);
  };

  float m_run = -1e30f, l_run = 0.f;
  f32x4 o[4] = {};

  stage(0, 0);
  __syncthreads();

  for (int kb = 0; kb < 32; ++kb) {
    const int cur = kb & 1;
    if (kb < 31) stage(cur ^ 1, (kb + 1) * 64);

    const unsigned short* ks = Ks[cur];
    const unsigned short* vs = Vs[cur];

    // S^T: s[nt] reg r = S[key = kb*64 + nt*16 + g*4 + r][q = m0 + c]
    f32x4 s[4] = {};
    for (int nt = 0; nt < 4; ++nt) {
      for (int kk = 0; kk < 2; ++kk) {
        int row = nt * 16 + c;
        int ch = (kk * 4 + g) ^ (c & 7);
        s16x8 ak = *(const s16x8*)((const char*)ks + row * 128 + ch * 16);
        s[nt] = __builtin_amdgcn_mfma_f32_16x16x32_bf16(ak, aq[kk], s[nt], 0, 0, 0);
      }
    }

    // online softmax (log2 domain; 1/sqrt(dk)*log2e folded into Q), per-lane row
    float tm = s[0][0];
    for (int nt = 0; nt < 4; ++nt)
      for (int r = 0; r < 4; ++r) tm = fmaxf(tm, s[nt][r]);
    tm = fmaxf(tm, __shfl_xor(tm, 16));
    tm = fmaxf(tm, __shfl_xor(tm, 32));
    if (!__all(tm - m_run <= 8.0f)) {  // defer-max: skip rescale when safe
      float mt = fmaxf(m_run, tm);
      float alpha = exp2f(m_run - mt);
      l_run *= alpha;
      for (int dt = 0; dt < 4; ++dt)
        for (int r = 0; r < 4; ++r) o[dt][r] *= alpha;
      m_run = mt;
    }
    float rs = 0.f;
    for (int nt = 0; nt < 4; ++nt)
      for (int r = 0; r < 4; ++r) {
        float p = exp2f(s[nt][r] - m_run);
        s[nt][r] = p;
        rs += p;
      }
    rs += __shfl_xor(rs, 16);
    rs += __shfl_xor(rs, 32);
    l_run += rs;

    // pack P -> per-wave LDS (XOR-swizzled [16 q][64 key], no pad)
    unsigned short* pw = Pw[w];
    for (int nt = 0; nt < 4; ++nt) {
      u32x2 pkd;
      pkd[0] = cvtpk_bf16(s[nt][0], s[nt][1]);
      pkd[1] = cvtpk_bf16(s[nt][2], s[nt][3]);
      int ch = (2 * nt + (g >> 1)) ^ (c & 7);
      *(u32x2*)((char*)pw + c * 128 + ch * 16 + (g & 1) * 8) = pkd;
    }

    // PV: o[dt] reg r = O^T[d = dt*16 + g*4 + r][q = m0 + c]
    for (int kk = 0; kk < 2; ++kk) {
      int pch = (kk * 4 + g) ^ (c & 7);
      s16x8 bp = *(const s16x8*)((const char*)pw + c * 128 + pch * 16);
      for (int dt = 0; dt < 4; ++dt) {
        int row = dt * 16 + c;
        int ch = (kk * 4 + g) ^ (c & 7);
        s16x8 av = *(const s16x8*)((const char*)vs + row * 128 + ch * 16);
        o[dt] = __builtin_amdgcn_mfma_f32_16x16x32_bf16(av, bp, o[dt], 0, 0, 0);
      }
    }
    __syncthreads();  // drains vmcnt (stage done) + lgkm; frees buf[cur]
  }

  // epilogue: lane writes row q = m0+c, d = dt*16 + g*4 + 0..3 (b64 stores)
  float inv = 1.0f / l_run;
  size_t base = ((size_t)b * 2048 + m0 + c) * 1024 + h * 64;
  for (int dt = 0; dt < 4; ++dt) {
    u16x4 pk;
    for (int r = 0; r < 4; ++r) pk[r] = f2bf(o[dt][r] * inv);
    *(u16x4*)(Att + base + dt * 16 + g * 4) = pk;
  }
}

// ---------------------------------------------------------------- launch
extern "C" void kernel_launch(void* const* d_in, const int* in_sizes, int n_in,
                              void* d_out, int out_size, void* d_ws, size_t ws_size,
                              hipStream_t stream) {
  const float* q = (const float*)d_in[0];
  const float* k = (const float*)d_in[1];
  const float* v = (const float*)d_in[2];
  const float* w_q = (const float*)d_in[3];
  const float* b_q = (const float*)d_in[4];
  const float* w_k = (const float*)d_in[5];
  const float* b_k = (const float*)d_in[6];
  const float* w_v = (const float*)d_in[7];
  const float* b_v = (const float*)d_in[8];
  const float* w_o = (const float*)d_in[9];
  const float* b_o = (const float*)d_in[10];

  unsigned short* s = (unsigned short*)d_ws;
  unsigned short* qbf = s;                   // 4096x1024 (reused for Att later)
  unsigned short* kbf = s + 4194304;
  unsigned short* vbf = s + 8388608;
  unsigned short* wqT = s + 12582912;        // 1024x1024 each
  unsigned short* wkT = s + 13631488;
  unsigned short* wvT = s + 14680064;
  unsigned short* woT = s + 15728640;
  unsigned short* Qp  = s + 16777216;        // 4096x1024
  unsigned short* Kp  = s + 20971520;
  unsigned short* Vt  = s + 25165824;        // end: 29360128 shorts = 56 MiB
  unsigned short* Att = qbf;                 // alias: qbf dead after k_gemm<0>

  const int NQKV = 4194304;
  k_cvt<<<2048, 256, 0, stream>>>(q, qbf, NQKV);
  k_cvt<<<2048, 256, 0, stream>>>(k, kbf, NQKV);
  k_cvt<<<2048, 256, 0, stream>>>(v, vbf, NQKV);

  dim3 tb(32, 8), tg(32, 32);
  k_wt<<<tg, tb, 0, stream>>>(w_q, wqT);
  k_wt<<<tg, tb, 0, stream>>>(w_k, wkT);
  k_wt<<<tg, tb, 0, stream>>>(w_v, wvT);
  k_wt<<<tg, tb, 0, stream>>>(w_o, woT);

  k_gemm<0><<<512, 256, 0, stream>>>(qbf, wqT, b_q, (void*)Qp);
  k_gemm<1><<<512, 256, 0, stream>>>(kbf, wkT, b_k, (void*)Kp);
  k_gemm<2><<<512, 256, 0, stream>>>(vbf, wvT, b_v, (void*)Vt);

  k_attn<<<1024, 256, 0, stream>>>(Qp, Kp, Vt, Att);

  k_gemm<3><<<512, 256, 0, stream>>>(Att, woT, b_o, d_out);
}

// Round 4
// 143.733 us; speedup vs baseline: 1.5036x; 1.1597x over previous
//
#include <hip/hip_runtime.h>
#include <stdint.h>

#define DEVI static __device__ __forceinline__

typedef float f32x4 __attribute__((ext_vector_type(4)));
typedef float f32x16 __attribute__((ext_vector_type(16)));
typedef short s16x8 __attribute__((ext_vector_type(8)));
typedef unsigned short u16x4 __attribute__((ext_vector_type(4)));
typedef uint32_t u32x2 __attribute__((ext_vector_type(2)));
typedef uint32_t u32x4 __attribute__((ext_vector_type(4)));

// f32 -> bf16 round-to-nearest-even
DEVI unsigned short f2bf(float f) {
  union { float f; uint32_t u; } v; v.f = f;
  uint32_t u = v.u;
  return (unsigned short)((u + 0x7fffu + ((u >> 16) & 1u)) >> 16);
}

// packed f32x2 -> bf16x2 (gfx950 v_cvt_pk_bf16_f32, RNE); lo in low 16 bits
DEVI uint32_t cvtpk(float lo, float hi) {
  uint32_t r;
  asm("v_cvt_pk_bf16_f32 %0, %1, %2" : "=v"(r) : "v"(lo), "v"(hi));
  return r;
}

// v_permlane32_swap_b32: a' = [a_lo, b_lo], b' = [a_hi, b_hi]
DEVI void pl32swap(uint32_t& a, uint32_t& b) {
#if __has_builtin(__builtin_amdgcn_permlane32_swap)
  u32x2 r = __builtin_amdgcn_permlane32_swap(a, b, false, false);
  a = r[0]; b = r[1];
#else
  asm("v_permlane32_swap_b32 %0, %1" : "+v"(a), "+v"(b));
#endif
}

// async 16B global -> LDS (linear dest: wave-uniform base + lane*16)
DEVI void g2l16(const void* g, void* l) {
  __builtin_amdgcn_global_load_lds(
      (const __attribute__((address_space(1))) void*)g,
      (__attribute__((address_space(3))) void*)l, 16, 0, 0);
}

// ---------------------------------------------------------------- convert x3
__global__ __launch_bounds__(256) void k_cvt3(const float* __restrict__ q,
                                              const float* __restrict__ k,
                                              const float* __restrict__ v,
                                              unsigned short* __restrict__ out) {
  const int y = blockIdx.y;
  const float* in = y == 0 ? q : y == 1 ? k : v;
  unsigned short* o = out + (size_t)y * 4194304;
  int idx = blockIdx.x * blockDim.x + threadIdx.x;
  int stride = gridDim.x * blockDim.x;
  for (int i = idx * 4; i < 4194304; i += stride * 4) {
    f32x4 x = *(const f32x4*)(in + i);
    u16x4 r;
    for (int j = 0; j < 4; ++j) r[j] = f2bf(x[j]);
    *(u16x4*)(o + i) = r;
  }
}

// ------------------------------------------- weight transpose+convert x4
__global__ __launch_bounds__(256) void k_wt4(const float* w0, const float* w1,
                                             const float* w2, const float* w3,
                                             unsigned short* t0, unsigned short* t1,
                                             unsigned short* t2, unsigned short* t3) {
  const int z = blockIdx.z;
  const float* w = z == 0 ? w0 : z == 1 ? w1 : z == 2 ? w2 : w3;
  unsigned short* wt = z == 0 ? t0 : z == 1 ? t1 : z == 2 ? t2 : t3;
  __shared__ float tile[32][33];
  const int tx = threadIdx.x, ty = threadIdx.y;
  const int n0 = blockIdx.x * 32, k0 = blockIdx.y * 32;
  for (int j = 0; j < 4; ++j)
    tile[ty + j * 8][tx] = w[(size_t)(k0 + ty + j * 8) * 1024 + n0 + tx];
  __syncthreads();
  for (int j = 0; j < 4; ++j)
    wt[(size_t)(n0 + ty + j * 8) * 1024 + k0 + tx] = f2bf(tile[tx][ty + j * 8]);
}

// ---------------------------------------------------------------- GEMM (bt)
// MODE (runtime) 0: Q proj bf16 (scaled by 0.125*log2e); 1: K proj bf16;
// 2: V proj -> Vt[(b*1024+n)*2048+t] bf16 (direct transposed store);
// 3: O proj f32. blockIdx.y selects the (A,Bt,bias,out) set; mode = mode0+y.
__global__ __launch_bounds__(256) void k_gemm_multi(
    const unsigned short* A0, const unsigned short* A1, const unsigned short* A2,
    const unsigned short* B0, const unsigned short* B1, const unsigned short* B2,
    const float* c0, const float* c1, const float* c2,
    void* o0, void* o1, void* o2, int mode0) {
  constexpr int K = 1024;
  const int z = blockIdx.y;
  const unsigned short* A = z == 0 ? A0 : z == 1 ? A1 : A2;
  const unsigned short* Bt = z == 0 ? B0 : z == 1 ? B1 : B2;
  const float* bias = z == 0 ? c0 : z == 1 ? c1 : c2;
  void* outp = z == 0 ? o0 : z == 1 ? o1 : o2;
  const int MODE = mode0 + z;

  __shared__ __align__(16) unsigned short As[128 * 64];
  __shared__ __align__(16) unsigned short Bs[64 * 64];
  const int tid = threadIdx.x;
  const int lane = tid & 63, w = tid >> 6;
  const int g = lane >> 4, c = lane & 15;
  const int bm = blockIdx.x >> 4, bn = blockIdx.x & 15;  // 32 x 16 blocks
  const int m0 = bm * 128, n0 = bn * 64;
  const int wr = w >> 1, wc = w & 1;  // wave tile: 64(m) x 32(n)
  f32x4 acc[4][2] = {};

  for (int kt = 0; kt < 16; ++kt) {
    const int k0 = kt * 64;
    __syncthreads();
    for (int it = 0; it < 4; ++it) {
      int e = it * 256 + tid;
      int row = e >> 3, cwp = (e & 7) ^ (row & 7);
      g2l16(A + (size_t)(m0 + row) * K + k0 + cwp * 8,
            (char*)As + (it * 256 + (w << 6)) * 16);
    }
    for (int it = 0; it < 2; ++it) {
      int e = it * 256 + tid;
      int row = e >> 3, cwp = (e & 7) ^ (row & 7);
      g2l16(Bt + (size_t)(n0 + row) * K + k0 + cwp * 8,
            (char*)Bs + (it * 256 + (w << 6)) * 16);
    }
    __syncthreads();
    for (int kk = 0; kk < 2; ++kk) {
      s16x8 af[4], bfr[2];
      for (int mi = 0; mi < 4; ++mi) {
        int row = wr * 64 + mi * 16 + c;
        int ch = (kk * 4 + g) ^ (row & 7);
        af[mi] = *(const s16x8*)((const char*)As + row * 128 + ch * 16);
      }
      for (int ni = 0; ni < 2; ++ni) {
        int row = wc * 32 + ni * 16 + c;
        int ch = (kk * 4 + g) ^ (row & 7);
        bfr[ni] = *(const s16x8*)((const char*)Bs + row * 128 + ch * 16);
      }
      for (int mi = 0; mi < 4; ++mi)
        for (int ni = 0; ni < 2; ++ni)
          acc[mi][ni] = __builtin_amdgcn_mfma_f32_16x16x32_bf16(
              af[mi], bfr[ni], acc[mi][ni], 0, 0, 0);
    }
  }

  if (MODE == 0 || MODE == 1) {
    unsigned short* out = (unsigned short*)outp;
    const float scale = (MODE == 0) ? 0.1803368801111204f : 1.0f;  // 0.125*log2e
    for (int mi = 0; mi < 4; ++mi)
      for (int ni = 0; ni < 2; ++ni) {
        int row = m0 + wr * 64 + mi * 16 + g * 4;
        int col = n0 + wc * 32 + ni * 16 + c;
        float bb = bias[col];
        for (int r = 0; r < 4; ++r)
          out[(size_t)(row + r) * 1024 + col] = f2bf((acc[mi][ni][r] + bb) * scale);
      }
  } else if (MODE == 2) {
    // direct transposed store: acc quad = 4 consecutive t at fixed n
    unsigned short* vt = (unsigned short*)outp;
    const int bq = m0 >> 11, t0 = m0 & 2047;
    for (int mi = 0; mi < 4; ++mi)
      for (int ni = 0; ni < 2; ++ni) {
        int rowb = wr * 64 + mi * 16 + g * 4;
        int coll = wc * 32 + ni * 16 + c;
        float bb = bias[n0 + coll];
        u16x4 pk;
        for (int r = 0; r < 4; ++r) pk[r] = f2bf(acc[mi][ni][r] + bb);
        *(u16x4*)(vt + (size_t)(bq * 1024 + n0 + coll) * 2048 + t0 + rowb) = pk;
      }
  } else {
    float* out = (float*)outp;
    for (int mi = 0; mi < 4; ++mi)
      for (int ni = 0; ni < 2; ++ni) {
        int row = m0 + wr * 64 + mi * 16 + g * 4;
        int col = n0 + wc * 32 + ni * 16 + c;
        float bb = bias[col];
        for (int r = 0; r < 4; ++r)
          out[(size_t)(row + r) * 1024 + col] = acc[mi][ni][r] + bb;
      }
  }
}

// ---------------------------------------------------------------- attention
// 32x32 MFMA flash attention, 32 q/wave, P fully in-register.
// S^T = mfma32(K, Q): lane holds q = lane&31, 32 keys at crow(r,hi).
// P built via cvt_pk + permlane32_swap (no LDS). O^T = mfma32(V^T, P):
// col = q = lane&31 matches softmax state -> per-lane rescale.
// K/V reg-staged (T14: load early, ds_write late), double-buffered.
__global__ __launch_bounds__(256) void k_attn(const unsigned short* __restrict__ Qp,
                                              const unsigned short* __restrict__ Kp,
                                              const unsigned short* __restrict__ Vt,
                                              unsigned short* __restrict__ Att) {
  __shared__ __align__(16) unsigned short Ks[2][4096];  // [64 key][64 d] swizzled
  __shared__ __align__(16) unsigned short Vs[2][4096];  // [64 d][64 key] swizzled
  const int tid = threadIdx.x;
  const int lane = tid & 63, w = tid >> 6;
  const int l31 = lane & 31, hi = lane >> 5;
  // XCD-chunked: 512 blocks, 64/XCD = 4 bh x 16 qt (K/V 2MB per XCD L2)
  const int blk = (blockIdx.x & 7) * 64 + (blockIdx.x >> 3);
  const int qt = blk & 15, bh = blk >> 4;
  const int b = bh >> 4, h = bh & 15;
  const int m0 = qt * 128 + w * 32;  // wave's q base
  const size_t qkBase = (size_t)b * 2048 * 1024 + (size_t)h * 64;
  const size_t vtBase = ((size_t)b * 1024 + h * 64) * 2048;

  // Q B-frags: lane holds Q[q=m0+l31][d = s*16 + hi*8 .. +7]
  const unsigned short* qrow = Qp + qkBase + (size_t)(m0 + l31) * 1024;
  s16x8 bq[4];
#pragma unroll
  for (int s = 0; s < 4; ++s)
    bq[s] = *(const s16x8*)(qrow + s * 16 + hi * 8);

  // staging: thread covers (row = tid>>2, 32B at col (tid&3)*16) of each tile
  const int srow = tid >> 2;
  const unsigned short* kg = Kp + qkBase + (size_t)srow * 1024 + (tid & 3) * 16;
  const unsigned short* vg = Vt + vtBase + (size_t)srow * 2048 + (tid & 3) * 16;
  const int wof0 = srow * 128 + ((((tid & 3) * 2 + 0) ^ (srow & 7)) * 16);
  const int wof1 = srow * 128 + ((((tid & 3) * 2 + 1) ^ (srow & 7)) * 16);

  float m_run = -1e30f, l_run = 0.f;
  f32x16 o0 = {}, o1 = {};

  // prologue: stage tile 0
  {
    s16x8 k0 = *(const s16x8*)(kg), k1 = *(const s16x8*)(kg + 8);
    s16x8 v0 = *(const s16x8*)(vg), v1 = *(const s16x8*)(vg + 8);
    *(s16x8*)((char*)&Ks[0][0] + wof0) = k0;
    *(s16x8*)((char*)&Ks[0][0] + wof1) = k1;
    *(s16x8*)((char*)&Vs[0][0] + wof0) = v0;
    *(s16x8*)((char*)&Vs[0][0] + wof1) = v1;
  }
  __syncthreads();

  const int rch = l31 & 7;  // row&7 for all LDS reads (rows = l31 mod 32)

#pragma unroll 1
  for (int t = 0; t < 32; ++t) {
    const int cur = t & 1;
    // T14 issue-early: next tile global -> regs
    s16x8 k0, k1, v0, v1;
    if (t < 31) {
      const unsigned short* kgt = kg + (size_t)(t + 1) * 64 * 1024;
      const unsigned short* vgt = vg + (t + 1) * 64;
      k0 = *(const s16x8*)(kgt);
      k1 = *(const s16x8*)(kgt + 8);
      v0 = *(const s16x8*)(vgt);
      v1 = *(const s16x8*)(vgt + 8);
    }
    const char* ks = (const char*)&Ks[cur][0];
    const char* vs = (const char*)&Vs[cur][0];

    // QK^T: S^T[key][q], key-blocks 0/1
    f32x16 s0 = {}, s1 = {};
    __builtin_amdgcn_s_setprio(1);
#pragma unroll
    for (int ds = 0; ds < 4; ++ds) {
      int ch = (2 * ds + hi) ^ rch;
      s16x8 a0 = *(const s16x8*)(ks + l31 * 128 + ch * 16);
      s16x8 a1 = *(const s16x8*)(ks + (32 + l31) * 128 + ch * 16);
      s0 = __builtin_amdgcn_mfma_f32_32x32x16_bf16(a0, bq[ds], s0, 0, 0, 0);
      s1 = __builtin_amdgcn_mfma_f32_32x32x16_bf16(a1, bq[ds], s1, 0, 0, 0);
    }
    __builtin_amdgcn_s_setprio(0);

    // online softmax (log2 domain), q = l31 per lane; halves combined by shfl(32)
    float tm = s0[0];
#pragma unroll
    for (int j = 1; j < 16; ++j) tm = fmaxf(tm, s0[j]);
#pragma unroll
    for (int j = 0; j < 16; ++j) tm = fmaxf(tm, s1[j]);
    tm = fmaxf(tm, __shfl_xor(tm, 32));
    if (!__all(tm - m_run <= 8.0f)) {  // defer-max
      float mt = fmaxf(m_run, tm);
      float al = exp2f(m_run - mt);
      l_run *= al;
#pragma unroll
      for (int j = 0; j < 16; ++j) { o0[j] *= al; o1[j] *= al; }
      m_run = mt;
    }
    float rs = 0.f;
#pragma unroll
    for (int j = 0; j < 16; ++j) { float p = exp2f(s0[j] - m_run); s0[j] = p; rs += p; }
#pragma unroll
    for (int j = 0; j < 16; ++j) { float p = exp2f(s1[j] - m_run); s1[j] = p; rs += p; }
    rs += __shfl_xor(rs, 32);
    l_run += rs;

    // P frags in-register: per key-block 8 cvt_pk + 4 permlane32_swap
    s16x8 pf[4];
    {
      uint32_t w0 = cvtpk(s0[0], s0[1]), w1 = cvtpk(s0[2], s0[3]);
      uint32_t w2 = cvtpk(s0[4], s0[5]), w3 = cvtpk(s0[6], s0[7]);
      uint32_t w4 = cvtpk(s0[8], s0[9]), w5 = cvtpk(s0[10], s0[11]);
      uint32_t w6 = cvtpk(s0[12], s0[13]), w7 = cvtpk(s0[14], s0[15]);
      pl32swap(w0, w2); pl32swap(w1, w3); pl32swap(w4, w6); pl32swap(w5, w7);
      u32x4 f0 = {w0, w1, w2, w3}, f1 = {w4, w5, w6, w7};
      pf[0] = *(s16x8*)&f0;
      pf[1] = *(s16x8*)&f1;
    }
    {
      uint32_t w0 = cvtpk(s1[0], s1[1]), w1 = cvtpk(s1[2], s1[3]);
      uint32_t w2 = cvtpk(s1[4], s1[5]), w3 = cvtpk(s1[6], s1[7]);
      uint32_t w4 = cvtpk(s1[8], s1[9]), w5 = cvtpk(s1[10], s1[11]);
      uint32_t w6 = cvtpk(s1[12], s1[13]), w7 = cvtpk(s1[14], s1[15]);
      pl32swap(w0, w2); pl32swap(w1, w3); pl32swap(w4, w6); pl32swap(w5, w7);
      u32x4 f0 = {w0, w1, w2, w3}, f1 = {w4, w5, w6, w7};
      pf[2] = *(s16x8*)&f0;
      pf[3] = *(s16x8*)&f1;
    }

    // PV: O^T[d][q] += V^T . P  (d-blocks 0/1)
    __builtin_amdgcn_s_setprio(1);
#pragma unroll
    for (int ksp = 0; ksp < 4; ++ksp) {
      int ch = (2 * ksp + hi) ^ rch;
      s16x8 a0 = *(const s16x8*)(vs + l31 * 128 + ch * 16);
      s16x8 a1 = *(const s16x8*)(vs + (32 + l31) * 128 + ch * 16);
      o0 = __builtin_amdgcn_mfma_f32_32x32x16_bf16(a0, pf[ksp], o0, 0, 0, 0);
      o1 = __builtin_amdgcn_mfma_f32_32x32x16_bf16(a1, pf[ksp], o1, 0, 0, 0);
    }
    __builtin_amdgcn_s_setprio(0);

    // T14 write-late: next tile regs -> LDS (other buffer)
    if (t < 31) {
      const int nb = cur ^ 1;
      *(s16x8*)((char*)&Ks[nb][0] + wof0) = k0;
      *(s16x8*)((char*)&Ks[nb][0] + wof1) = k1;
      *(s16x8*)((char*)&Vs[nb][0] + wof0) = v0;
      *(s16x8*)((char*)&Vs[nb][0] + wof1) = v1;
    }
    __syncthreads();
  }

  // epilogue: lane writes q-row m0+l31; d = dblk*32 + 8*rq + 4*hi + 0..3
  float inv = 1.0f / l_run;
  unsigned short* arow = Att + ((size_t)b * 2048 + m0 + l31) * 1024 + h * 64;
#pragma unroll
  for (int dblk = 0; dblk < 2; ++dblk) {
#pragma unroll
    for (int rq = 0; rq < 4; ++rq) {
      float e0 = (dblk ? o1[rq * 4 + 0] : o0[rq * 4 + 0]) * inv;
      float e1 = (dblk ? o1[rq * 4 + 1] : o0[rq * 4 + 1]) * inv;
      float e2 = (dblk ? o1[rq * 4 + 2] : o0[rq * 4 + 2]) * inv;
      float e3 = (dblk ? o1[rq * 4 + 3] : o0[rq * 4 + 3]) * inv;
      u32x2 pk;
      pk[0] = cvtpk(e0, e1);
      pk[1] = cvtpk(e2, e3);
      *(u32x2*)(arow + dblk * 32 + 8 * rq + 4 * hi) = pk;
    }
  }
}

// ---------------------------------------------------------------- launch
extern "C" void kernel_launch(void* const* d_in, const int* in_sizes, int n_in,
                              void* d_out, int out_size, void* d_ws, size_t ws_size,
                              hipStream_t stream) {
  const float* q = (const float*)d_in[0];
  const float* k = (const float*)d_in[1];
  const float* v = (const float*)d_in[2];
  const float* w_q = (const float*)d_in[3];
  const float* b_q = (const float*)d_in[4];
  const float* w_k = (const float*)d_in[5];
  const float* b_k = (const float*)d_in[6];
  const float* w_v = (const float*)d_in[7];
  const float* b_v = (const float*)d_in[8];
  const float* w_o = (const float*)d_in[9];
  const float* b_o = (const float*)d_in[10];

  unsigned short* s = (unsigned short*)d_ws;
  unsigned short* qbf = s;                   // 4096x1024 (reused for Att later)
  unsigned short* kbf = s + 4194304;
  unsigned short* vbf = s + 8388608;
  unsigned short* wqT = s + 12582912;        // 1024x1024 each
  unsigned short* wkT = s + 13631488;
  unsigned short* wvT = s + 14680064;
  unsigned short* woT = s + 15728640;
  unsigned short* Qp  = s + 16777216;        // 4096x1024
  unsigned short* Kp  = s + 20971520;
  unsigned short* Vt  = s + 25165824;        // end: 29360128 shorts = 56 MiB
  unsigned short* Att = qbf;                 // alias: qbf dead after QKV GEMM

  k_cvt3<<<dim3(1024, 3), 256, 0, stream>>>(q, k, v, qbf);

  k_wt4<<<dim3(32, 32, 4), dim3(32, 8), 0, stream>>>(w_q, w_k, w_v, w_o,
                                                     wqT, wkT, wvT, woT);

  k_gemm_multi<<<dim3(512, 3), 256, 0, stream>>>(
      qbf, kbf, vbf, wqT, wkT, wvT, b_q, b_k, b_v,
      (void*)Qp, (void*)Kp, (void*)Vt, 0);

  k_attn<<<512, 256, 0, stream>>>(Qp, Kp, Vt, Att);

  k_gemm_multi<<<dim3(512, 1), 256, 0, stream>>>(
      Att, Att, Att, woT, woT, woT, b_o, b_o, b_o,
      d_out, d_out, d_out, 3);
}